// Round 1
// baseline (441.449 us; speedup 1.0000x reference)
//
#include <hip/hip_runtime.h>

#define DIM 1024
#define NQ 6

// One 256-thread block per row (grid-stride). Thread t owns out[d0..d0+3], d0=4t.
// Weights cached per-thread in registers: w1 frag 24f, w2 frag 24f, b2 4f.
// Per-row: coalesced float4 x load -> 24 FMA partials -> folded butterfly
// (10 shuffles) -> 24B LDS cross-wave combine (1 barrier, parity dbuf) ->
// cos -> 24 FMA + relu -> coalesced float4 store.
__global__ __launch_bounds__(256, 4) void ffq_fused(
    const float* __restrict__ x,
    const float* __restrict__ w1,
    const float* __restrict__ b1,
    const float* __restrict__ theta,
    const float* __restrict__ w2,
    const float* __restrict__ b2,
    float* __restrict__ out,
    int n_rows)
{
    const int t    = threadIdx.x;
    const int lane = t & 63;
    const int wave = t >> 6;
    const int d0   = t * 4;

    // ---- register-cached weights (reused across all rows) ----
    float w1f[NQ][4];
#pragma unroll
    for (int q = 0; q < NQ; ++q) {
        float4 v = *reinterpret_cast<const float4*>(w1 + q * DIM + d0);
        w1f[q][0] = v.x; w1f[q][1] = v.y; w1f[q][2] = v.z; w1f[q][3] = v.w;
    }
    float w2f[4][NQ];  // w2f[i][q] = w2[(d0+i)*6 + q]; 24 contiguous floats, 16B aligned
    {
        const float4* wp = reinterpret_cast<const float4*>(w2 + (size_t)d0 * NQ);
        float* flat = &w2f[0][0];
#pragma unroll
        for (int i = 0; i < 6; ++i) {
            float4 v = wp[i];
            flat[4 * i + 0] = v.x; flat[4 * i + 1] = v.y;
            flat[4 * i + 2] = v.z; flat[4 * i + 3] = v.w;
        }
    }
    const float4 b2v = *reinterpret_cast<const float4*>(b2 + d0);
    float b1f[NQ], ctf[NQ];
#pragma unroll
    for (int q = 0; q < NQ; ++q) {
        b1f[q] = b1[q];
        ctf[q] = __cosf(theta[q]);
    }

    // value index this lane ends up holding after the folded butterfly
    const int vperm = 4 * (lane & 1) + 2 * ((lane >> 1) & 1) + ((lane >> 2) & 1);

    __shared__ float red[2][4][8];  // [parity][wave][value]

    const int stride = gridDim.x;
    int r = blockIdx.x;
    int par = 0;

    float4 xv = make_float4(0.f, 0.f, 0.f, 0.f);
    if (r < n_rows) xv = *reinterpret_cast<const float4*>(x + (size_t)r * DIM + d0);

    while (r < n_rows) {
        // prefetch next row before the reduction/barrier
        const int rn = r + stride;
        float4 xn = make_float4(0.f, 0.f, 0.f, 0.f);
        if (rn < n_rows) xn = *reinterpret_cast<const float4*>(x + (size_t)rn * DIM + d0);

        // partial dot of this thread's 4 elements against each w1 row
        float p[8];
#pragma unroll
        for (int q = 0; q < NQ; ++q)
            p[q] = fmaf(xv.x, w1f[q][0],
                   fmaf(xv.y, w1f[q][1],
                   fmaf(xv.z, w1f[q][2], xv.w * w1f[q][3])));
        p[6] = 0.f; p[7] = 0.f;

        // folded butterfly: 8 values x 64 lanes -> lane holds wave-total of value vperm
        float r4[4];
        {
            const bool up = (lane & 1) != 0;
#pragma unroll
            for (int i = 0; i < 4; ++i) {
                float send = up ? p[i] : p[i + 4];
                float keep = up ? p[i + 4] : p[i];
                r4[i] = keep + __shfl_xor(send, 1, 64);
            }
        }
        float r2[2];
        {
            const bool up = (lane & 2) != 0;
#pragma unroll
            for (int i = 0; i < 2; ++i) {
                float send = up ? r4[i] : r4[i + 2];
                float keep = up ? r4[i + 2] : r4[i];
                r2[i] = keep + __shfl_xor(send, 2, 64);
            }
        }
        float r1;
        {
            const bool up = (lane & 4) != 0;
            float send = up ? r2[0] : r2[1];
            float keep = up ? r2[1] : r2[0];
            r1 = keep + __shfl_xor(send, 4, 64);
        }
        r1 += __shfl_xor(r1, 8, 64);
        r1 += __shfl_xor(r1, 16, 64);
        r1 += __shfl_xor(r1, 32, 64);

        if (lane < 8 && vperm < NQ) red[par][wave][vperm] = r1;
        __syncthreads();

        // combine 4 wave partials (broadcast LDS reads), cos, then output frag
        float qv[NQ];
#pragma unroll
        for (int q = 0; q < NQ; ++q) {
            float s = red[par][0][q] + red[par][1][q] +
                      red[par][2][q] + red[par][3][q];
            qv[q] = __cosf(s + b1f[q]) * ctf[q];
        }

        float4 o = b2v;
#pragma unroll
        for (int q = 0; q < NQ; ++q) {
            o.x = fmaf(qv[q], w2f[0][q], o.x);
            o.y = fmaf(qv[q], w2f[1][q], o.y);
            o.z = fmaf(qv[q], w2f[2][q], o.z);
            o.w = fmaf(qv[q], w2f[3][q], o.w);
        }
        o.x = fmaxf(o.x, 0.f); o.y = fmaxf(o.y, 0.f);
        o.z = fmaxf(o.z, 0.f); o.w = fmaxf(o.w, 0.f);
        *reinterpret_cast<float4*>(out + (size_t)r * DIM + d0) = o;

        xv = xn;
        r = rn;
        par ^= 1;
    }
}

extern "C" void kernel_launch(void* const* d_in, const int* in_sizes, int n_in,
                              void* d_out, int out_size, void* d_ws, size_t ws_size,
                              hipStream_t stream) {
    const float* x     = (const float*)d_in[0];
    const float* w1    = (const float*)d_in[1];
    const float* b1    = (const float*)d_in[2];
    const float* theta = (const float*)d_in[3];
    const float* w2    = (const float*)d_in[4];
    const float* b2    = (const float*)d_in[5];
    float* out = (float*)d_out;

    const int n_rows = in_sizes[0] / DIM;  // B*S = 65536
    const int blocks = 1024;               // 4 blocks/CU resident at <=128 VGPR
    ffq_fused<<<blocks, 256, 0, stream>>>(x, w1, b1, theta, w2, b2, out, n_rows);
}